// Round 9
// baseline (2406.497 us; speedup 1.0000x reference)
//
#include <hip/hip_runtime.h>

#define Bsz 128
#define Tn  1024
#define Dn  256
#define Hn  256
#define NXP 248   // xproj worker WGs (blockIdx 8..255)

typedef _Float16 f16;
typedef _Float16 f16x4 __attribute__((ext_vector_type(4)));
typedef _Float16 f16x8 __attribute__((ext_vector_type(8)));
typedef float f32x4 __attribute__((ext_vector_type(4)));
typedef unsigned long long u64;

#define MF(A, B, C) __builtin_amdgcn_mfma_f32_16x16x32_f16((A), (B), (C), 0, 0, 0)
#define ALOAD(p)     __hip_atomic_load((p),      __ATOMIC_RELAXED, __HIP_MEMORY_SCOPE_AGENT)
#define ASTORE(p, v) __hip_atomic_store((p), (v), __ATOMIC_RELAXED, __HIP_MEMORY_SCOPE_AGENT)

// Per-t readiness flags for pre[t] (set by xproj workers after their agent
// stores retire; consumed by the 8 recurrent WGs). Self-cleaning: the LAST
// recurrent WG (g_done counter) resets them -> correct across graph replays.
__device__ int g_pflag[1032];
__device__ int g_done;

// Exact tanh: 1 - 2/(e^{2x}+1) via v_exp_f32. err ~1e-6, saturates correctly.
__device__ __forceinline__ float tanh_fast(float x) {
    float e = __builtin_amdgcn_exp2f(x * 2.88539008177793f);  // e^{2x}
    return 1.0f - 2.0f * __builtin_amdgcn_rcpf(e + 1.0f);
}

// LDS-only barrier (lgkmcnt drain, no vmcnt): global loads/stores stay in
// flight across steps (pre prefetch latency is hidden across the barrier).
__device__ __forceinline__ void wg_barrier() {
    asm volatile("s_waitcnt lgkmcnt(0)\n\ts_barrier" ::: "memory");
}

// h fragment-major layout: element (m=batch 0..15, k=0..255) lives at
// f16 offset (k>>5)*512 + ((k>>3)&3)*128 + m*8 + (k&7).
// A wave's B-fragment read for K-block kk is 16B at kk*512 + lane*8
// -> stride-1 lane-contiguous, conflict-free.

// ---------------------------------------------------------------------------
// ONE kernel, 256 WGs x 512 thr:
//  blocks 0..7   : recurrent loop (both layers + head, 1 barrier/step) for
//                  b-group g = blockIdx; pre[t] via agent u64 loads gated by
//                  g_pflag[t] (1-step prefetched). R9: phase-B accumulator
//                  SPLIT into accX/accH -> 6 independent 8-deep MFMA chains
//                  per wave (was 2x8 + 2x16; the 16-deep chains serialized
//                  ~500cy/step of dependent-MFMA latency).
//  blocks 8..255 : xproj workers, register-direct (no LDS staging).
//  LDS statically padded to 84 KB => 1 WG/CU.
// Deadlock-free: workers never wait; consumers spin only on flags that
// workers set unconditionally.
// ---------------------------------------------------------------------------
__global__ __launch_bounds__(512, 1) void k_all(
    const float* __restrict__ x,    const float* __restrict__ Wxh0,
    const float* __restrict__ b0v,  const float* __restrict__ Whh0,
    const float* __restrict__ Wxh1, const float* __restrict__ Whh1,
    const float* __restrict__ b1v,  const float* __restrict__ fcw,
    const float* __restrict__ fcb,  float* __restrict__ preT,
    float* __restrict__ out)
{
    __shared__ __align__(16) f16 smem[43008];  // 84 KB: forces 1 WG/CU
    __shared__ int sflag;

    const int tid  = threadIdx.x;
    const int lane = tid & 63, l15 = lane & 15, quad = lane >> 4;
    const int w    = tid >> 6;
    const int colbase = w * 32;

    if (blockIdx.x >= 8) {
        // ===================== XPROJ WORKER (register-direct) ==============
        const int w2 = blockIdx.x - 8;

        // A-fragments of Wxh0 (j = colbase + jn*16 + l15), vectorized
        f16x8 wf[2][8];
        #pragma unroll
        for (int jn = 0; jn < 2; jn++) {
            int j = colbase + jn * 16 + l15;
            #pragma unroll
            for (int kk = 0; kk < 8; kk++) {
                const float* wp = Wxh0 + (size_t)j * Dn + kk * 32 + quad * 8;
                float4 a = *(const float4*)(wp);
                float4 b = *(const float4*)(wp + 4);
                wf[jn][kk] = (f16x8){ (f16)a.x, (f16)a.y, (f16)a.z, (f16)a.w,
                                      (f16)b.x, (f16)b.y, (f16)b.z, (f16)b.w };
            }
        }
        float4 bx[2];
        #pragma unroll
        for (int jn = 0; jn < 2; jn++)
            bx[jn] = *(const float4*)(b0v + colbase + jn * 16 + quad * 4);

        #pragma unroll 1
        for (int t = w2; t < Tn; t += NXP) {
            // B-fragments of x_t straight from global: lane (quad,l15) at
            // (bblk,kk) needs x[bblk*16+l15][t][kk*32+quad*8 .. +7].
            #pragma unroll
            for (int bblk = 0; bblk < 8; bblk++) {
                const float* xp = x + ((size_t)(bblk * 16 + l15) * Tn + t) * Dn + quad * 8;
                f16x8 xb[8];
                #pragma unroll
                for (int kk = 0; kk < 8; kk++) {
                    float4 a = *(const float4*)(xp + kk * 32);
                    float4 b = *(const float4*)(xp + kk * 32 + 4);
                    xb[kk] = (f16x8){ (f16)a.x, (f16)a.y, (f16)a.z, (f16)a.w,
                                      (f16)b.x, (f16)b.y, (f16)b.z, (f16)b.w };
                }
                f32x4 acc0 = (f32x4){bx[0].x, bx[0].y, bx[0].z, bx[0].w};
                f32x4 acc1 = (f32x4){bx[1].x, bx[1].y, bx[1].z, bx[1].w};
                #pragma unroll
                for (int kk = 0; kk < 8; kk++) {
                    acc0 = MF(wf[0][kk], xb[kk], acc0);
                    acc1 = MF(wf[1][kk], xb[kk], acc1);
                }
                // pre[t][b][j]: agent stores (consumers on other XCDs read at
                // the coherence point)
                size_t fi0 = ((size_t)t * Bsz + bblk * 16 + l15) * Hn + colbase + quad * 4;
                union { f32x4 v; u64 u[2]; } c0; c0.v = acc0;
                ASTORE((u64*)preT + (fi0 >> 1),     c0.u[0]);
                ASTORE((u64*)preT + (fi0 >> 1) + 1, c0.u[1]);
                union { f32x4 v; u64 u[2]; } c1; c1.v = acc1;
                ASTORE((u64*)preT + (fi0 >> 1) + 8, c1.u[0]);
                ASTORE((u64*)preT + (fi0 >> 1) + 9, c1.u[1]);
            }
            // retire this t's stores, then publish
            asm volatile("s_waitcnt vmcnt(0)" ::: "memory");
            __syncthreads();
            if (tid == 0) ASTORE(&g_pflag[t], 1);
        }
        return;
    }

    // ===================== RECURRENT =====================
    f16* h1f0 = smem;
    f16* h1f1 = smem + 4096;
    f16* h2f0 = smem + 8192;
    f16* h2f1 = smem + 12288;
    const int bg = blockIdx.x * 16;

    for (int i = tid; i < 16384; i += 512) smem[i] = (f16)0.0f;

    // weight A-fragments (vectorized loads): row j = colbase + jn*16 + l15
    f16x8 wh0[2][8], wx[2][8], wh1[2][8];
    #pragma unroll
    for (int jn = 0; jn < 2; jn++) {
        int j = colbase + jn * 16 + l15;
        #pragma unroll
        for (int kk = 0; kk < 8; kk++) {
            size_t o = (size_t)j * Hn + kk * 32 + quad * 8;
            float4 a, b;
            a = *(const float4*)(Whh0 + o); b = *(const float4*)(Whh0 + o + 4);
            wh0[jn][kk] = (f16x8){ (f16)a.x, (f16)a.y, (f16)a.z, (f16)a.w,
                                   (f16)b.x, (f16)b.y, (f16)b.z, (f16)b.w };
            a = *(const float4*)(Wxh1 + o); b = *(const float4*)(Wxh1 + o + 4);
            wx[jn][kk]  = (f16x8){ (f16)a.x, (f16)a.y, (f16)a.z, (f16)a.w,
                                   (f16)b.x, (f16)b.y, (f16)b.z, (f16)b.w };
            a = *(const float4*)(Whh1 + o); b = *(const float4*)(Whh1 + o + 4);
            wh1[jn][kk] = (f16x8){ (f16)a.x, (f16)a.y, (f16)a.z, (f16)a.w,
                                   (f16)b.x, (f16)b.y, (f16)b.z, (f16)b.w };
        }
    }
    float4 bi[2];
    #pragma unroll
    for (int jn = 0; jn < 2; jn++)
        bi[jn] = *(const float4*)(b1v + colbase + jn * 16 + quad * 4);

    int wroff[2];
    #pragma unroll
    for (int jn = 0; jn < 2; jn++) {
        int n0 = colbase + jn * 16 + quad * 4;
        wroff[jn] = (n0 >> 5) * 512 + ((n0 >> 3) & 3) * 128 + l15 * 8 + (n0 & 7);
    }

    // pre[t][bg+l15][colbase + jn*16 + quad*4 + r] as u64 pairs
    const u64* ppu = (const u64*)preT +
                     ((((size_t)(bg + l15)) * Hn + colbase + quad * 4) >> 1);

    // startup: wait for pre[0], load it; prefetch flag for pre[1]
    int fval = ALOAD(&g_pflag[0]);
    while (fval < 1) { __builtin_amdgcn_s_sleep(8); fval = ALOAD(&g_pflag[0]); }
    asm volatile("" ::: "memory");
    u64 pnu0 = ALOAD(ppu),     pnu1 = ALOAD(ppu + 1);
    u64 pnu2 = ALOAD(ppu + 8), pnu3 = ALOAD(ppu + 9);
    fval = ALOAD(&g_pflag[1]);
    __syncthreads();

// accA <- pre[t] currently in pnu (xproj already added b0)
#define UNPACK_ACCA \
    f32x4 accA[2]; \
    { union { u64 u[2]; f32x4 v; } c0, c1; \
      c0.u[0] = pnu0; c0.u[1] = pnu1; c1.u[0] = pnu2; c1.u[1] = pnu3; \
      accA[0] = c0.v; accA[1] = c1.v; }

// check flag for pre[I+1] (fval = prefetched g_pflag[I+1]); prefetch
// pre[I+1] into pnu and g_pflag[I+2] into fval. Spin only if behind.
#define PREFETCH(I) { \
    int fnew = ALOAD(&g_pflag[(I) + 2]); \
    if (fval < 1) { \
        do { __builtin_amdgcn_s_sleep(2); fval = ALOAD(&g_pflag[(I) + 1]); } \
        while (fval < 1); \
    } \
    asm volatile("" ::: "memory"); \
    const u64* pq = ppu + (size_t)((I) + 1) * ((Bsz * Hn) >> 1); \
    pnu0 = ALOAD(pq);     pnu1 = ALOAD(pq + 1); \
    pnu2 = ALOAD(pq + 8); pnu3 = ALOAD(pq + 9); \
    fval = fnew; }

// One step: h1[I] = tanh(pre[I] + Whh0.h1[I-1] (H1R)) -> H1W;
//           h2[I-1] = tanh(b1 + Wxh1.h1[I-1] (hb1) + Whh1.h2[I-2] (H2R))
//           -> H2W. h1 tail between the MFMA blocks. ONE barrier.
// R9: accX/accH split -> 6 independent 8-deep chains (accA x2, accX x2,
// accH x2); accX+accH summed in the tanh tail (8 v_add_f32).
#define FSTEP(H1R, H1W, H2R, H2W, I) { \
    UNPACK_ACCA \
    PREFETCH(I) \
    f16x8 hb1[8]; \
    _Pragma("unroll") for (int kk = 0; kk < 8; kk++) { \
        hb1[kk] = *(const f16x8*)((H1R) + kk * 512 + lane * 8); \
        accA[0] = MF(wh0[0][kk], hb1[kk], accA[0]); \
        accA[1] = MF(wh0[1][kk], hb1[kk], accA[1]); \
    } \
    _Pragma("unroll") for (int jn = 0; jn < 2; jn++) { \
        f16x4 t1v = { (f16)tanh_fast(accA[jn][0]), (f16)tanh_fast(accA[jn][1]), \
                      (f16)tanh_fast(accA[jn][2]), (f16)tanh_fast(accA[jn][3]) }; \
        *(f16x4*)((H1W) + wroff[jn]) = t1v; \
    } \
    f32x4 accX[2], accH[2]; \
    accX[0] = (f32x4){bi[0].x, bi[0].y, bi[0].z, bi[0].w}; \
    accX[1] = (f32x4){bi[1].x, bi[1].y, bi[1].z, bi[1].w}; \
    accH[0] = (f32x4){0.f, 0.f, 0.f, 0.f}; \
    accH[1] = (f32x4){0.f, 0.f, 0.f, 0.f}; \
    _Pragma("unroll") for (int kk = 0; kk < 8; kk++) { \
        f16x8 hb2 = *(const f16x8*)((H2R) + kk * 512 + lane * 8); \
        accX[0] = MF(wx [0][kk], hb1[kk], accX[0]); \
        accX[1] = MF(wx [1][kk], hb1[kk], accX[1]); \
        accH[0] = MF(wh1[0][kk], hb2, accH[0]); \
        accH[1] = MF(wh1[1][kk], hb2, accH[1]); \
    } \
    _Pragma("unroll") for (int jn = 0; jn < 2; jn++) { \
        f16x4 t2v = { (f16)tanh_fast(accX[jn][0] + accH[jn][0]), \
                      (f16)tanh_fast(accX[jn][1] + accH[jn][1]), \
                      (f16)tanh_fast(accX[jn][2] + accH[jn][2]), \
                      (f16)tanh_fast(accX[jn][3] + accH[jn][3]) }; \
        *(f16x4*)((H2W) + wroff[jn]) = t2v; \
    } \
    wg_barrier(); \
}

// Last full step (I = 1023): pnu already holds pre[1023]; no flag/prefetch.
#define FSTEP_LAST(H1R, H1W, H2R, H2W) { \
    UNPACK_ACCA \
    f16x8 hb1[8]; \
    _Pragma("unroll") for (int kk = 0; kk < 8; kk++) { \
        hb1[kk] = *(const f16x8*)((H1R) + kk * 512 + lane * 8); \
        accA[0] = MF(wh0[0][kk], hb1[kk], accA[0]); \
        accA[1] = MF(wh0[1][kk], hb1[kk], accA[1]); \
    } \
    _Pragma("unroll") for (int jn = 0; jn < 2; jn++) { \
        f16x4 t1v = { (f16)tanh_fast(accA[jn][0]), (f16)tanh_fast(accA[jn][1]), \
                      (f16)tanh_fast(accA[jn][2]), (f16)tanh_fast(accA[jn][3]) }; \
        *(f16x4*)((H1W) + wroff[jn]) = t1v; \
    } \
    f32x4 accX[2], accH[2]; \
    accX[0] = (f32x4){bi[0].x, bi[0].y, bi[0].z, bi[0].w}; \
    accX[1] = (f32x4){bi[1].x, bi[1].y, bi[1].z, bi[1].w}; \
    accH[0] = (f32x4){0.f, 0.f, 0.f, 0.f}; \
    accH[1] = (f32x4){0.f, 0.f, 0.f, 0.f}; \
    _Pragma("unroll") for (int kk = 0; kk < 8; kk++) { \
        f16x8 hb2 = *(const f16x8*)((H2R) + kk * 512 + lane * 8); \
        accX[0] = MF(wx [0][kk], hb1[kk], accX[0]); \
        accX[1] = MF(wx [1][kk], hb1[kk], accX[1]); \
        accH[0] = MF(wh1[0][kk], hb2, accH[0]); \
        accH[1] = MF(wh1[1][kk], hb2, accH[1]); \
    } \
    _Pragma("unroll") for (int jn = 0; jn < 2; jn++) { \
        f16x4 t2v = { (f16)tanh_fast(accX[jn][0] + accH[jn][0]), \
                      (f16)tanh_fast(accX[jn][1] + accH[jn][1]), \
                      (f16)tanh_fast(accX[jn][2] + accH[jn][2]), \
                      (f16)tanh_fast(accX[jn][3] + accH[jn][3]) }; \
        *(f16x4*)((H2W) + wroff[jn]) = t2v; \
    } \
    wg_barrier(); \
}

    // --- peeled i = 0: h1[0] only (h2[-1] stays zero) ---
    {
        UNPACK_ACCA
        PREFETCH(0)
        #pragma unroll
        for (int kk = 0; kk < 8; kk++) {
            f16x8 hb = *(const f16x8*)(h1f1 + kk * 512 + lane * 8);  // zeros
            accA[0] = MF(wh0[0][kk], hb, accA[0]);
            accA[1] = MF(wh0[1][kk], hb, accA[1]);
        }
        #pragma unroll
        for (int jn = 0; jn < 2; jn++) {
            f16x4 t1v = { (f16)tanh_fast(accA[jn][0]), (f16)tanh_fast(accA[jn][1]),
                          (f16)tanh_fast(accA[jn][2]), (f16)tanh_fast(accA[jn][3]) };
            *(f16x4*)(h1f0 + wroff[jn]) = t1v;
        }
        wg_barrier();
    }

    // --- steady state: i = 1..1022 ---
    #pragma unroll 1
    for (int tp = 0; tp < 511; ++tp) {
        FSTEP(h1f0, h1f1, h2f1, h2f0, (2 * tp + 1))
        FSTEP(h1f1, h1f0, h2f0, h2f1, (2 * tp + 2))
    }
    // --- i = 1023 ---
    FSTEP_LAST(h1f0, h1f1, h2f1, h2f0)
#undef FSTEP
#undef FSTEP_LAST
#undef PREFETCH
#undef UNPACK_ACCA

    // --- peeled i = 1024: h2[1023] = tanh(b1 + Wxh1.h1[1023] + Whh1.h2[1022])
    {
        f32x4 accX[2], accH[2];
        accX[0] = (f32x4){bi[0].x, bi[0].y, bi[0].z, bi[0].w};
        accX[1] = (f32x4){bi[1].x, bi[1].y, bi[1].z, bi[1].w};
        accH[0] = (f32x4){0.f, 0.f, 0.f, 0.f};
        accH[1] = (f32x4){0.f, 0.f, 0.f, 0.f};
        #pragma unroll
        for (int kk = 0; kk < 8; kk++) {
            f16x8 hb1 = *(const f16x8*)(h1f1 + kk * 512 + lane * 8);  // h1[1023]
            f16x8 hb2 = *(const f16x8*)(h2f0 + kk * 512 + lane * 8);  // h2[1022]
            accX[0] = MF(wx [0][kk], hb1, accX[0]);
            accX[1] = MF(wx [1][kk], hb1, accX[1]);
            accH[0] = MF(wh1[0][kk], hb2, accH[0]);
            accH[1] = MF(wh1[1][kk], hb2, accH[1]);
        }
        #pragma unroll
        for (int jn = 0; jn < 2; jn++) {
            f16x4 t2v = { (f16)tanh_fast(accX[jn][0] + accH[jn][0]),
                          (f16)tanh_fast(accX[jn][1] + accH[jn][1]),
                          (f16)tanh_fast(accX[jn][2] + accH[jn][2]),
                          (f16)tanh_fast(accX[jn][3] + accH[jn][3]) };
            *(f16x4*)(h2f1 + wroff[jn]) = t2v;
        }
        wg_barrier();
    }

    // head: final h2[1023] in h2f1; frag-major.
    if (tid < 256) {
        const int bl = tid >> 4, o = (tid >> 3) & 1, kc = tid & 7;
        float s = 0.f;
        #pragma unroll
        for (int kq = 0; kq < 32; kq++) {
            int k = kc * 32 + kq;
            f16 hv = h2f1[(k >> 5) * 512 + ((k >> 3) & 3) * 128 + bl * 8 + (k & 7)];
            s += (float)hv * fcw[o * Hn + k];
        }
        s += __shfl_down(s, 4);
        s += __shfl_down(s, 2);
        s += __shfl_down(s, 1);
        if (kc == 0)
            out[(bg + bl) * 2 + o] = s + fcb[o];
    }

    // flag self-clean: LAST of the 8 recurrent WGs (all consumers provably
    // done) resets g_pflag + g_done for the next launch / graph replay.
    __syncthreads();
    if (tid == 0) {
        int old = atomicAdd(&g_done, 1);
        sflag = (old == 7) ? 1 : 0;
    }
    __syncthreads();
    if (sflag) {
        for (int i = tid; i < 1032; i += 512) ASTORE(&g_pflag[i], 0);
        if (tid == 0) ASTORE(&g_done, 0);
    }
}

extern "C" void kernel_launch(void* const* d_in, const int* in_sizes, int n_in,
                              void* d_out, int out_size, void* d_ws, size_t ws_size,
                              hipStream_t stream) {
    const float* x    = (const float*)d_in[0];
    const float* Wxh0 = (const float*)d_in[1];
    const float* Whh0 = (const float*)d_in[2];
    const float* b0   = (const float*)d_in[3];
    const float* Wxh1 = (const float*)d_in[4];
    const float* Whh1 = (const float*)d_in[5];
    const float* b1   = (const float*)d_in[6];
    const float* fcw  = (const float*)d_in[7];
    const float* fcb  = (const float*)d_in[8];
    float* out = (float*)d_out;

    float* preT = (float*)d_ws;  // pre[t][b][j] fp32 = 128 MiB

    k_all<<<dim3(256), dim3(512), 0, stream>>>(x, Wxh0, b0, Whh0, Wxh1, Whh1,
                                               b1, fcw, fcb, preT, out);
}

// Round 10
// 1454.569 us; speedup vs baseline: 1.6544x; 1.6544x over previous
//
#include <hip/hip_runtime.h>

#define Bsz 128
#define Tn  1024
#define Dn  256
#define Hn  256

typedef _Float16 f16;
typedef _Float16 f16x4 __attribute__((ext_vector_type(4)));
typedef _Float16 f16x8 __attribute__((ext_vector_type(8)));
typedef float f32x4 __attribute__((ext_vector_type(4)));

#define MF(A, B, C) __builtin_amdgcn_mfma_f32_16x16x32_f16((A), (B), (C), 0, 0, 0)

// Exact tanh: 1 - 2/(e^{2x}+1) via v_exp_f32. err ~1e-6, saturates correctly.
__device__ __forceinline__ float tanh_fast(float x) {
    float e = __builtin_amdgcn_exp2f(x * 2.88539008177793f);  // e^{2x}
    return 1.0f - 2.0f * __builtin_amdgcn_rcpf(e + 1.0f);
}

// LDS-only barrier (lgkmcnt drain, no vmcnt) so global prefetch loads stay
// in flight across steps.
__device__ __forceinline__ void wg_barrier() {
    asm volatile("s_waitcnt lgkmcnt(0)\n\ts_barrier" ::: "memory");
}

// h fragment-major LDS layout: element (m=batch 0..15, k=0..255) lives at
// f16 offset (k>>5)*512 + ((k>>3)&3)*128 + m*8 + (k&7).
// A wave's B-fragment read for K-block kk is then ds_read_b128 at
// kk*1024B + lane*16B -> stride-1 lane-contiguous, conflict-free.

// ---------------------------------------------------------------------------
// K1: pre[t][b][j] = x[b][t][:] . Wxh0[j][:] + b0[j]   (fp32 in/out)
// REGISTER-DIRECT (r7/r8 lesson: LDS staging serialized HBM latency into a
// 32-deep load->cvt->ds_write chain, ~60us/t; register fragments pipeline 16
// independent loads per bblk and L2 absorbs the 8x/WG x_t reuse, r8-measured).
// grid = 256 WGs x 512 thr (8 waves x 32 j-cols), 4 consecutive t per WG.
// ---------------------------------------------------------------------------
__global__ __launch_bounds__(512, 1) void k_xproj(
    const float* __restrict__ x, const float* __restrict__ W,
    const float* __restrict__ bias, float* __restrict__ preT)
{
    const int tid  = threadIdx.x;
    const int lane = tid & 63, l15 = lane & 15, quad = lane >> 4;
    const int w    = tid >> 6;
    const int colbase = w * 32;

    // A-fragments of Wxh0 (j = colbase + jn*16 + l15), vectorized
    f16x8 wf[2][8];
    #pragma unroll
    for (int jn = 0; jn < 2; jn++) {
        int j = colbase + jn * 16 + l15;
        #pragma unroll
        for (int kk = 0; kk < 8; kk++) {
            const float* wp = W + (size_t)j * Dn + kk * 32 + quad * 8;
            float4 a = *(const float4*)(wp);
            float4 b = *(const float4*)(wp + 4);
            wf[jn][kk] = (f16x8){ (f16)a.x, (f16)a.y, (f16)a.z, (f16)a.w,
                                  (f16)b.x, (f16)b.y, (f16)b.z, (f16)b.w };
        }
    }
    float4 bx[2];
    #pragma unroll
    for (int jn = 0; jn < 2; jn++)
        bx[jn] = *(const float4*)(bias + colbase + jn * 16 + quad * 4);

    #pragma unroll 1
    for (int tt = 0; tt < 4; tt++) {
        const int t = blockIdx.x * 4 + tt;   // consecutive t: x locality
        #pragma unroll
        for (int bblk = 0; bblk < 8; bblk++) {
            const float* xp = x + ((size_t)(bblk * 16 + l15) * Tn + t) * Dn + quad * 8;
            f16x8 xb[8];
            #pragma unroll
            for (int kk = 0; kk < 8; kk++) {
                float4 a = *(const float4*)(xp + kk * 32);
                float4 b = *(const float4*)(xp + kk * 32 + 4);
                xb[kk] = (f16x8){ (f16)a.x, (f16)a.y, (f16)a.z, (f16)a.w,
                                  (f16)b.x, (f16)b.y, (f16)b.z, (f16)b.w };
            }
            f32x4 acc0 = (f32x4){bx[0].x, bx[0].y, bx[0].z, bx[0].w};
            f32x4 acc1 = (f32x4){bx[1].x, bx[1].y, bx[1].z, bx[1].w};
            #pragma unroll
            for (int kk = 0; kk < 8; kk++) {
                acc0 = MF(wf[0][kk], xb[kk], acc0);
                acc1 = MF(wf[1][kk], xb[kk], acc1);
            }
            // pre[t][b][j]: lane holds j = colbase + jn*16 + quad*4 + r,
            // b = bblk*16 + l15 -> 2x float4 stores
            float* pp = preT + ((size_t)t * Bsz + bblk * 16 + l15) * Hn
                             + colbase + quad * 4;
            *(f32x4*)(pp)      = acc0;
            *(f32x4*)(pp + 16) = acc1;
        }
    }
}

// ---------------------------------------------------------------------------
// K2 (R3's proven kernel, byte-identical): layer-pipelined, tail-hoisted,
// branch-free loop. Per step i, ONE barrier:
//   h1[i]   = tanh(pre[i] + Whh0 . h1[i-1])                  (accA, 2x 8-deep)
//   h2[i-1] = tanh(b1 + Wxh1 . h1[i-1] + Whh1 . h2[i-2])     (accB, 2x 16-deep)
// h1 tail between the MFMA blocks (schedules into the accB shadow); hb1
// fragments shared across both blocks. i=0/1023/1024 peeled (branch-free
// steady state -- r1: in-loop branches spill; r9: NO accumulator growth,
// the loop is at the 128-VGPR allocation point with zero headroom).
// 8 WGs x 512 thr; weights as A-fragments in registers.
// ---------------------------------------------------------------------------
__global__ __launch_bounds__(512, 1) void k_fused(
    const float* __restrict__ Whh0, const float* __restrict__ Wxh1,
    const float* __restrict__ Whh1, const float* __restrict__ b1v,
    const float* __restrict__ fcw,  const float* __restrict__ fcb,
    const float* __restrict__ preT, float* __restrict__ out)
{
    __shared__ __align__(16) f16 h1f[2][4096];  // 8 KB each, frag-major
    __shared__ __align__(16) f16 h2f[2][4096];

    const int tid  = threadIdx.x;
    const int lane = tid & 63, l15 = lane & 15, quad = lane >> 4;
    const int w    = tid >> 6;
    const int colbase = w * 32;
    const int bg   = blockIdx.x * 16;

    for (int i = tid; i < 4096; i += 512) {
        h1f[0][i] = (f16)0.0f; h1f[1][i] = (f16)0.0f;
        h2f[0][i] = (f16)0.0f; h2f[1][i] = (f16)0.0f;
    }

    // A-fragments: row j = colbase + jn*16 + l15, k = kk*32 + quad*8 + e
    f16x8 wh0[2][8], wx[2][8], wh1[2][8];
    #pragma unroll
    for (int jn = 0; jn < 2; jn++) {
        int j = colbase + jn * 16 + l15;
        #pragma unroll
        for (int kk = 0; kk < 8; kk++)
            #pragma unroll
            for (int e = 0; e < 8; e++) {
                int o = (int)((size_t)j * Hn + kk * 32 + quad * 8 + e);
                wh0[jn][kk][e] = (f16)Whh0[o];
                wx [jn][kk][e] = (f16)Wxh1[o];
                wh1[jn][kk][e] = (f16)Whh1[o];
            }
    }
    float4 bi[2];
    #pragma unroll
    for (int jn = 0; jn < 2; jn++)
        bi[jn] = *(const float4*)(b1v + colbase + jn * 16 + quad * 4);

    // write offsets for the h epilogue (per jn): 4 consecutive k = n0..n0+3
    int wroff[2];
    #pragma unroll
    for (int jn = 0; jn < 2; jn++) {
        int n0 = colbase + jn * 16 + quad * 4;
        wroff[jn] = (n0 >> 5) * 512 + ((n0 >> 3) & 3) * 128 + l15 * 8 + (n0 & 7);
    }

    // prefetch pointer: pre[t][bg+l15][colbase + jn*16 + quad*4 + r]
    const float* pp = preT + ((size_t)(bg + l15)) * Hn + colbase + quad * 4;

    // pn holds pre[t] (as 2x float4) at entry to step t
    f32x4 pnv[2];
    pnv[0] = *(const f32x4*)(pp);
    pnv[1] = *(const f32x4*)(pp + 16);
    __syncthreads();

// Steady-state pipelined step, NO branches. PR = I&1 (compile-time).
// Reads h1[i-1] from h1f[PR^1], h2[i-2] from h2f[PR];
// writes h1[i] -> h1f[PR], h2[i-1] -> h2f[PR^1]. Prefetches pre[TF].
#define FSTEP_FULL(PR, I, TF) { \
    f32x4 accA[2]; \
    accA[0] = pnv[0]; accA[1] = pnv[1]; \
    pnv[0] = *(const f32x4*)(pp + (size_t)(TF) * (Bsz * Hn)); \
    pnv[1] = *(const f32x4*)(pp + (size_t)(TF) * (Bsz * Hn) + 16); \
    f16x8 hb1[8]; \
    _Pragma("unroll") for (int kk = 0; kk < 8; kk++) { \
        hb1[kk] = *(const f16x8*)(&h1f[(PR)^1][kk * 512 + lane * 8]); \
        accA[0] = MF(wh0[0][kk], hb1[kk], accA[0]); \
        accA[1] = MF(wh0[1][kk], hb1[kk], accA[1]); \
    } \
    /* h1 tail here: schedules into the accB MFMA shadow */ \
    _Pragma("unroll") for (int jn = 0; jn < 2; jn++) { \
        f16x4 t1v = { (f16)tanh_fast(accA[jn][0]), (f16)tanh_fast(accA[jn][1]), \
                      (f16)tanh_fast(accA[jn][2]), (f16)tanh_fast(accA[jn][3]) }; \
        *(f16x4*)(&h1f[(PR)][wroff[jn]]) = t1v; \
    } \
    f32x4 accB[2]; \
    _Pragma("unroll") for (int jn = 0; jn < 2; jn++) \
        accB[jn] = (f32x4){bi[jn].x, bi[jn].y, bi[jn].z, bi[jn].w}; \
    _Pragma("unroll") for (int kk = 0; kk < 8; kk++) { \
        f16x8 hb2 = *(const f16x8*)(&h2f[(PR)][kk * 512 + lane * 8]); \
        accB[0] = MF(wx [0][kk], hb1[kk], accB[0]); \
        accB[1] = MF(wx [1][kk], hb1[kk], accB[1]); \
        accB[0] = MF(wh1[0][kk], hb2, accB[0]); \
        accB[1] = MF(wh1[1][kk], hb2, accB[1]); \
    } \
    _Pragma("unroll") for (int jn = 0; jn < 2; jn++) { \
        f16x4 t2v = { (f16)tanh_fast(accB[jn][0]), (f16)tanh_fast(accB[jn][1]), \
                      (f16)tanh_fast(accB[jn][2]), (f16)tanh_fast(accB[jn][3]) }; \
        *(f16x4*)(&h2f[(PR)^1][wroff[jn]]) = t2v; \
    } \
    wg_barrier(); \
}

    // --- peeled i = 0: h1[0] = tanh(pre[0] + Whh0 . 0); NO h2 write ---
    {
        f32x4 accA[2];
        accA[0] = pnv[0]; accA[1] = pnv[1];
        pnv[0] = *(const f32x4*)(pp + (size_t)1 * (Bsz * Hn));
        pnv[1] = *(const f32x4*)(pp + (size_t)1 * (Bsz * Hn) + 16);
        #pragma unroll
        for (int kk = 0; kk < 8; kk++) {
            f16x8 hb1 = *(const f16x8*)(&h1f[1][kk * 512 + lane * 8]);  // zeros
            accA[0] = MF(wh0[0][kk], hb1, accA[0]);
            accA[1] = MF(wh0[1][kk], hb1, accA[1]);
        }
        #pragma unroll
        for (int jn = 0; jn < 2; jn++) {
            f16x4 t1v = { (f16)tanh_fast(accA[jn][0]), (f16)tanh_fast(accA[jn][1]),
                          (f16)tanh_fast(accA[jn][2]), (f16)tanh_fast(accA[jn][3]) };
            *(f16x4*)(&h1f[0][wroff[jn]]) = t1v;
        }
        wg_barrier();
    }

    // --- steady state: i = 1..1022, branch-free ---
    #pragma unroll 1
    for (int tp = 0; tp < 511; ++tp) {
        const int t1 = 2 * tp + 1;
        FSTEP_FULL(1, t1, (t1 + 1))
        FSTEP_FULL(0, (t1 + 1), (t1 + 2))
    }
    // --- peeled i = 1023 (prefetch target clamped; pn unused afterwards) ---
    FSTEP_FULL(1, 1023, 1023)
#undef FSTEP_FULL

    // --- peeled i = 1024: h2[1023] = tanh(b1 + Wxh1.h1[1023] + Whh1.h2[1022])
    {
        f32x4 accB[2];
        #pragma unroll
        for (int jn = 0; jn < 2; jn++)
            accB[jn] = (f32x4){bi[jn].x, bi[jn].y, bi[jn].z, bi[jn].w};
        #pragma unroll
        for (int kk = 0; kk < 8; kk++) {
            f16x8 hb1 = *(const f16x8*)(&h1f[1][kk * 512 + lane * 8]);  // h1[1023]
            f16x8 hb2 = *(const f16x8*)(&h2f[0][kk * 512 + lane * 8]);  // h2[1022]
            accB[0] = MF(wx [0][kk], hb1, accB[0]);
            accB[1] = MF(wx [1][kk], hb1, accB[1]);
            accB[0] = MF(wh1[0][kk], hb2, accB[0]);
            accB[1] = MF(wh1[1][kk], hb2, accB[1]);
        }
        #pragma unroll
        for (int jn = 0; jn < 2; jn++) {
            f16x4 t2v = { (f16)tanh_fast(accB[jn][0]), (f16)tanh_fast(accB[jn][1]),
                          (f16)tanh_fast(accB[jn][2]), (f16)tanh_fast(accB[jn][3]) };
            *(f16x4*)(&h2f[1][wroff[jn]]) = t2v;
        }
        wg_barrier();
    }

    // head: final h2[1023] in h2f[1]; frag-major.
    if (tid < 256) {
        const int bl = tid >> 4, o = (tid >> 3) & 1, kc = tid & 7;
        float s = 0.f;
        #pragma unroll
        for (int kq = 0; kq < 32; kq++) {
            int k = kc * 32 + kq;
            f16 hv = h2f[1][(k >> 5) * 512 + ((k >> 3) & 3) * 128 + bl * 8 + (k & 7)];
            s += (float)hv * fcw[o * Hn + k];
        }
        s += __shfl_down(s, 4);
        s += __shfl_down(s, 2);
        s += __shfl_down(s, 1);
        if (kc == 0)
            out[(bg + bl) * 2 + o] = s + fcb[o];
    }
}

extern "C" void kernel_launch(void* const* d_in, const int* in_sizes, int n_in,
                              void* d_out, int out_size, void* d_ws, size_t ws_size,
                              hipStream_t stream) {
    const float* x    = (const float*)d_in[0];
    const float* Wxh0 = (const float*)d_in[1];
    const float* Whh0 = (const float*)d_in[2];
    const float* b0   = (const float*)d_in[3];
    const float* Wxh1 = (const float*)d_in[4];
    const float* Whh1 = (const float*)d_in[5];
    const float* b1   = (const float*)d_in[6];
    const float* fcw  = (const float*)d_in[7];
    const float* fcb  = (const float*)d_in[8];
    float* out = (float*)d_out;

    float* preT = (float*)d_ws;  // pre[t][b][j] fp32 = 128 MiB

    k_xproj<<<dim3(256), dim3(512), 0, stream>>>(x, Wxh0, b0, preT);
    k_fused<<<dim3(Bsz / 16), dim3(512), 0, stream>>>(Whh0, Wxh1, Whh1, b1,
                                                      fcw, fcb, preT, out);
}

// Round 11
// 1374.959 us; speedup vs baseline: 1.7502x; 1.0579x over previous
//
#include <hip/hip_runtime.h>

#define Bsz 128
#define Tn  1024
#define Dn  256
#define Hn  256

typedef _Float16 f16;
typedef _Float16 f16x4 __attribute__((ext_vector_type(4)));
typedef _Float16 f16x8 __attribute__((ext_vector_type(8)));
typedef float f32x4 __attribute__((ext_vector_type(4)));

#define MF(A, B, C) __builtin_amdgcn_mfma_f32_16x16x32_f16((A), (B), (C), 0, 0, 0)

// x pre-converted to f16 once (bit-identical to the in-kernel (f16) casts all
// prior versions did). 64 MiB static BSS (proven pattern, r4-r9).
__device__ __align__(16) f16 g_x16[(size_t)Bsz * Tn * Dn];

// Exact tanh: 1 - 2/(e^{2x}+1) via v_exp_f32. err ~1e-6, saturates correctly.
__device__ __forceinline__ float tanh_fast(float x) {
    float e = __builtin_amdgcn_exp2f(x * 2.88539008177793f);  // e^{2x}
    return 1.0f - 2.0f * __builtin_amdgcn_rcpf(e + 1.0f);
}

// LDS-only barrier (lgkmcnt drain, no vmcnt) so global prefetch loads stay
// in flight across steps.
__device__ __forceinline__ void wg_barrier() {
    asm volatile("s_waitcnt lgkmcnt(0)\n\ts_barrier" ::: "memory");
}

// ---------------------------------------------------------------------------
// K0: x (f32 [b][t][d]) -> g_x16 (f16, same layout). Pure streaming
// elementwise (G13): float4x2 loads -> f16x8 stores, grid-stride.
// ---------------------------------------------------------------------------
__global__ __launch_bounds__(256, 4) void k_cvt(const float* __restrict__ x)
{
    const size_t total = (size_t)Bsz * Tn * Dn;
    size_t i = ((size_t)blockIdx.x * 256 + threadIdx.x) * 8;
    const size_t stride = (size_t)gridDim.x * 256 * 8;
    for (; i < total; i += stride) {
        float4 a = *(const float4*)(x + i);
        float4 b = *(const float4*)(x + i + 4);
        f16x8 v = { (f16)a.x, (f16)a.y, (f16)a.z, (f16)a.w,
                    (f16)b.x, (f16)b.y, (f16)b.z, (f16)b.w };
        *(f16x8*)(g_x16 + i) = v;
    }
}

// ---------------------------------------------------------------------------
// K1: pre[t][b][j] = x[b][t][:] . Wxh0[j][:] + b0[j]   (f32 out)
// One WG = (16-b group) x (8-t chunk): its x16 slice is 16 contiguous 4KB
// runs (vs per-t 1KB gathers in r0-r6, or 8x-redundant reg-direct cvt in
// r10). Staged as 16 independent 16B loads/thread (NO conversions, NO
// dependent chain) into frag-major LDS; compute reads the proven
// conflict-free kk*512+lane*8 pattern (same as k_fused).
// grid = 8 bgroups x 128 tchunks = 1024 WGs, 256 thr (4 waves x 64 j).
// LDS 64 KB -> 2 WGs/CU.
// ---------------------------------------------------------------------------
__global__ __launch_bounds__(256, 2) void k_xproj(
    const float* __restrict__ W, const float* __restrict__ bias,
    float* __restrict__ preT)
{
    __shared__ __align__(16) f16 xs[8 * 4096];  // [t][frag-major 16b x 256k]

    const int tid  = threadIdx.x;
    const int lane = tid & 63, l15 = lane & 15, quad = lane >> 4;
    const int w    = tid >> 6;
    const int bgi  = blockIdx.x >> 7;     // 0..7   (b-group)
    const int tc   = blockIdx.x & 127;    // 0..127 (t-chunk)
    const int t0 = tc * 8, brange = bgi * 16;

    // A-fragments of Wxh0 (j = w*64 + jn*16 + l15), vectorized f32 loads
    f16x8 wf[4][8];
    #pragma unroll
    for (int jn = 0; jn < 4; jn++) {
        int j = w * 64 + jn * 16 + l15;
        #pragma unroll
        for (int kk = 0; kk < 8; kk++) {
            const float* wp = W + (size_t)j * Dn + kk * 32 + quad * 8;
            float4 a = *(const float4*)(wp);
            float4 b = *(const float4*)(wp + 4);
            wf[jn][kk] = (f16x8){ (f16)a.x, (f16)a.y, (f16)a.z, (f16)a.w,
                                  (f16)b.x, (f16)b.y, (f16)b.z, (f16)b.w };
        }
    }
    float4 bx[4];
    #pragma unroll
    for (int jn = 0; jn < 4; jn++)
        bx[jn] = *(const float4*)(bias + w * 64 + jn * 16 + quad * 4);

    // stage 64 KB: chunk c covers f16 index L = (c*256+tid)*8 of xs.
    // Decomp: t=L>>12, kk=(L>>9)&7, qs=(L>>7)&3, bs=(L>>3)&15; the source
    // element block is g_x16[(brange+bs)][t0+t][kk*32+qs*8 .. +7].
    // 16 independent 16B loads -> 16 ds_writes (no chain, no cvt).
    f16x8 stg[16];
    #pragma unroll
    for (int c = 0; c < 16; c++) {
        int L = (c * 256 + tid) * 8;
        int t = L >> 12, kk = (L >> 9) & 7, qs = (L >> 7) & 3, bs = (L >> 3) & 15;
        stg[c] = *(const f16x8*)(g_x16 +
                    ((size_t)(brange + bs) * Tn + (t0 + t)) * Dn + kk * 32 + qs * 8);
    }
    #pragma unroll
    for (int c = 0; c < 16; c++)
        *(f16x8*)(&xs[(c * 256 + tid) * 8]) = stg[c];
    __syncthreads();

    #pragma unroll 1
    for (int t = 0; t < 8; t++) {
        f32x4 acc[4];
        #pragma unroll
        for (int jn = 0; jn < 4; jn++)
            acc[jn] = (f32x4){bx[jn].x, bx[jn].y, bx[jn].z, bx[jn].w};
        #pragma unroll
        for (int kk = 0; kk < 8; kk++) {
            f16x8 xb = *(const f16x8*)(&xs[t * 4096 + kk * 512 + lane * 8]);
            #pragma unroll
            for (int jn = 0; jn < 4; jn++)
                acc[jn] = MF(wf[jn][kk], xb, acc[jn]);
        }
        // C-layout: lane holds j = w*64+jn*16+quad*4+r, b = brange+l15
        #pragma unroll
        for (int jn = 0; jn < 4; jn++) {
            int j0 = w * 64 + jn * 16 + quad * 4;
            *(f32x4*)(preT + ((size_t)(t0 + t) * Bsz + brange + l15) * Hn + j0)
                = acc[jn];
        }
    }
}

// ---------------------------------------------------------------------------
// K2 (R3's proven kernel, byte-identical): layer-pipelined, tail-hoisted,
// branch-free loop. Per step i, ONE barrier:
//   h1[i]   = tanh(pre[i] + Whh0 . h1[i-1])                  (accA, 2x 8-deep)
//   h2[i-1] = tanh(b1 + Wxh1 . h1[i-1] + Whh1 . h2[i-2])     (accB, 2x 16-deep)
// h1 tail between the MFMA blocks (schedules into the accB shadow); hb1
// fragments shared across both blocks. i=0/1023/1024 peeled (branch-free
// steady state -- r1: in-loop branches spill; r9: NO accumulator growth,
// the loop is at the 128-VGPR allocation point with zero headroom).
// 8 WGs x 512 thr; weights as A-fragments in registers.
// ---------------------------------------------------------------------------
__global__ __launch_bounds__(512, 1) void k_fused(
    const float* __restrict__ Whh0, const float* __restrict__ Wxh1,
    const float* __restrict__ Whh1, const float* __restrict__ b1v,
    const float* __restrict__ fcw,  const float* __restrict__ fcb,
    const float* __restrict__ preT, float* __restrict__ out)
{
    __shared__ __align__(16) f16 h1f[2][4096];  // 8 KB each, frag-major
    __shared__ __align__(16) f16 h2f[2][4096];

    const int tid  = threadIdx.x;
    const int lane = tid & 63, l15 = lane & 15, quad = lane >> 4;
    const int w    = tid >> 6;
    const int colbase = w * 32;
    const int bg   = blockIdx.x * 16;

    for (int i = tid; i < 4096; i += 512) {
        h1f[0][i] = (f16)0.0f; h1f[1][i] = (f16)0.0f;
        h2f[0][i] = (f16)0.0f; h2f[1][i] = (f16)0.0f;
    }

    // A-fragments: row j = colbase + jn*16 + l15, k = kk*32 + quad*8 + e
    f16x8 wh0[2][8], wx[2][8], wh1[2][8];
    #pragma unroll
    for (int jn = 0; jn < 2; jn++) {
        int j = colbase + jn * 16 + l15;
        #pragma unroll
        for (int kk = 0; kk < 8; kk++)
            #pragma unroll
            for (int e = 0; e < 8; e++) {
                int o = (int)((size_t)j * Hn + kk * 32 + quad * 8 + e);
                wh0[jn][kk][e] = (f16)Whh0[o];
                wx [jn][kk][e] = (f16)Wxh1[o];
                wh1[jn][kk][e] = (f16)Whh1[o];
            }
    }
    float4 bi[2];
    #pragma unroll
    for (int jn = 0; jn < 2; jn++)
        bi[jn] = *(const float4*)(b1v + colbase + jn * 16 + quad * 4);

    // write offsets for the h epilogue (per jn): 4 consecutive k = n0..n0+3
    int wroff[2];
    #pragma unroll
    for (int jn = 0; jn < 2; jn++) {
        int n0 = colbase + jn * 16 + quad * 4;
        wroff[jn] = (n0 >> 5) * 512 + ((n0 >> 3) & 3) * 128 + l15 * 8 + (n0 & 7);
    }

    // prefetch pointer: pre[t][bg+l15][colbase + jn*16 + quad*4 + r]
    const float* pp = preT + ((size_t)(bg + l15)) * Hn + colbase + quad * 4;

    // pn holds pre[t] (as 2x float4) at entry to step t
    f32x4 pnv[2];
    pnv[0] = *(const f32x4*)(pp);
    pnv[1] = *(const f32x4*)(pp + 16);
    __syncthreads();

// Steady-state pipelined step, NO branches. PR = I&1 (compile-time).
// Reads h1[i-1] from h1f[PR^1], h2[i-2] from h2f[PR];
// writes h1[i] -> h1f[PR], h2[i-1] -> h2f[PR^1]. Prefetches pre[TF].
#define FSTEP_FULL(PR, I, TF) { \
    f32x4 accA[2]; \
    accA[0] = pnv[0]; accA[1] = pnv[1]; \
    pnv[0] = *(const f32x4*)(pp + (size_t)(TF) * (Bsz * Hn)); \
    pnv[1] = *(const f32x4*)(pp + (size_t)(TF) * (Bsz * Hn) + 16); \
    f16x8 hb1[8]; \
    _Pragma("unroll") for (int kk = 0; kk < 8; kk++) { \
        hb1[kk] = *(const f16x8*)(&h1f[(PR)^1][kk * 512 + lane * 8]); \
        accA[0] = MF(wh0[0][kk], hb1[kk], accA[0]); \
        accA[1] = MF(wh0[1][kk], hb1[kk], accA[1]); \
    } \
    /* h1 tail here: schedules into the accB MFMA shadow */ \
    _Pragma("unroll") for (int jn = 0; jn < 2; jn++) { \
        f16x4 t1v = { (f16)tanh_fast(accA[jn][0]), (f16)tanh_fast(accA[jn][1]), \
                      (f16)tanh_fast(accA[jn][2]), (f16)tanh_fast(accA[jn][3]) }; \
        *(f16x4*)(&h1f[(PR)][wroff[jn]]) = t1v; \
    } \
    f32x4 accB[2]; \
    _Pragma("unroll") for (int jn = 0; jn < 2; jn++) \
        accB[jn] = (f32x4){bi[jn].x, bi[jn].y, bi[jn].z, bi[jn].w}; \
    _Pragma("unroll") for (int kk = 0; kk < 8; kk++) { \
        f16x8 hb2 = *(const f16x8*)(&h2f[(PR)][kk * 512 + lane * 8]); \
        accB[0] = MF(wx [0][kk], hb1[kk], accB[0]); \
        accB[1] = MF(wx [1][kk], hb1[kk], accB[1]); \
        accB[0] = MF(wh1[0][kk], hb2, accB[0]); \
        accB[1] = MF(wh1[1][kk], hb2, accB[1]); \
    } \
    _Pragma("unroll") for (int jn = 0; jn < 2; jn++) { \
        f16x4 t2v = { (f16)tanh_fast(accB[jn][0]), (f16)tanh_fast(accB[jn][1]), \
                      (f16)tanh_fast(accB[jn][2]), (f16)tanh_fast(accB[jn][3]) }; \
        *(f16x4*)(&h2f[(PR)^1][wroff[jn]]) = t2v; \
    } \
    wg_barrier(); \
}

    // --- peeled i = 0: h1[0] = tanh(pre[0] + Whh0 . 0); NO h2 write ---
    {
        f32x4 accA[2];
        accA[0] = pnv[0]; accA[1] = pnv[1];
        pnv[0] = *(const f32x4*)(pp + (size_t)1 * (Bsz * Hn));
        pnv[1] = *(const f32x4*)(pp + (size_t)1 * (Bsz * Hn) + 16);
        #pragma unroll
        for (int kk = 0; kk < 8; kk++) {
            f16x8 hb1 = *(const f16x8*)(&h1f[1][kk * 512 + lane * 8]);  // zeros
            accA[0] = MF(wh0[0][kk], hb1, accA[0]);
            accA[1] = MF(wh0[1][kk], hb1, accA[1]);
        }
        #pragma unroll
        for (int jn = 0; jn < 2; jn++) {
            f16x4 t1v = { (f16)tanh_fast(accA[jn][0]), (f16)tanh_fast(accA[jn][1]),
                          (f16)tanh_fast(accA[jn][2]), (f16)tanh_fast(accA[jn][3]) };
            *(f16x4*)(&h1f[0][wroff[jn]]) = t1v;
        }
        wg_barrier();
    }

    // --- steady state: i = 1..1022, branch-free ---
    #pragma unroll 1
    for (int tp = 0; tp < 511; ++tp) {
        const int t1 = 2 * tp + 1;
        FSTEP_FULL(1, t1, (t1 + 1))
        FSTEP_FULL(0, (t1 + 1), (t1 + 2))
    }
    // --- peeled i = 1023 (prefetch target clamped; pn unused afterwards) ---
    FSTEP_FULL(1, 1023, 1023)
#undef FSTEP_FULL

    // --- peeled i = 1024: h2[1023] = tanh(b1 + Wxh1.h1[1023] + Whh1.h2[1022])
    {
        f32x4 accB[2];
        #pragma unroll
        for (int jn = 0; jn < 2; jn++)
            accB[jn] = (f32x4){bi[jn].x, bi[jn].y, bi[jn].z, bi[jn].w};
        #pragma unroll
        for (int kk = 0; kk < 8; kk++) {
            f16x8 hb1 = *(const f16x8*)(&h1f[1][kk * 512 + lane * 8]);  // h1[1023]
            f16x8 hb2 = *(const f16x8*)(&h2f[0][kk * 512 + lane * 8]);  // h2[1022]
            accB[0] = MF(wx [0][kk], hb1, accB[0]);
            accB[1] = MF(wx [1][kk], hb1, accB[1]);
            accB[0] = MF(wh1[0][kk], hb2, accB[0]);
            accB[1] = MF(wh1[1][kk], hb2, accB[1]);
        }
        #pragma unroll
        for (int jn = 0; jn < 2; jn++) {
            f16x4 t2v = { (f16)tanh_fast(accB[jn][0]), (f16)tanh_fast(accB[jn][1]),
                          (f16)tanh_fast(accB[jn][2]), (f16)tanh_fast(accB[jn][3]) };
            *(f16x4*)(&h2f[1][wroff[jn]]) = t2v;
        }
        wg_barrier();
    }

    // head: final h2[1023] in h2f[1]; frag-major.
    if (tid < 256) {
        const int bl = tid >> 4, o = (tid >> 3) & 1, kc = tid & 7;
        float s = 0.f;
        #pragma unroll
        for (int kq = 0; kq < 32; kq++) {
            int k = kc * 32 + kq;
            f16 hv = h2f[1][(k >> 5) * 512 + ((k >> 3) & 3) * 128 + bl * 8 + (k & 7)];
            s += (float)hv * fcw[o * Hn + k];
        }
        s += __shfl_down(s, 4);
        s += __shfl_down(s, 2);
        s += __shfl_down(s, 1);
        if (kc == 0)
            out[(bg + bl) * 2 + o] = s + fcb[o];
    }
}

extern "C" void kernel_launch(void* const* d_in, const int* in_sizes, int n_in,
                              void* d_out, int out_size, void* d_ws, size_t ws_size,
                              hipStream_t stream) {
    const float* x    = (const float*)d_in[0];
    const float* Wxh0 = (const float*)d_in[1];
    const float* Whh0 = (const float*)d_in[2];
    const float* b0   = (const float*)d_in[3];
    const float* Wxh1 = (const float*)d_in[4];
    const float* Whh1 = (const float*)d_in[5];
    const float* b1   = (const float*)d_in[6];
    const float* fcw  = (const float*)d_in[7];
    const float* fcb  = (const float*)d_in[8];
    float* out = (float*)d_out;

    float* preT = (float*)d_ws;  // pre[t][b][j] fp32 = 128 MiB

    k_cvt  <<<dim3(2048), dim3(256), 0, stream>>>(x);
    k_xproj<<<dim3(1024), dim3(256), 0, stream>>>(Wxh0, b0, preT);
    k_fused<<<dim3(Bsz / 16), dim3(512), 0, stream>>>(Whh0, Wxh1, Whh1, b1,
                                                      fcw, fcb, preT, out);
}